// Round 9
// baseline (413.253 us; speedup 1.0000x reference)
//
#include <hip/hip_runtime.h>
#include <hip/hip_fp16.h>

// Sudoku GNN: 5x GCNConv (shared graph) + 2-layer MLP head.
// CSR via two-level bucket sort (no global atomics). Weight-free CSR
// (dinv factored into producers/consumers). Pull-based aggs fused with
// the following dense stage through LDS row staging.
// Confirmed levers: fp16 on all gathered arrays (R4/R5); k_scat LDS
// bucket-sort (R8, write-amp 5.3x -> ~1.5x). Dead levers: occupancy>47%
// for the gather (R1-R3); 256B-in-flight bursts (R6); 2048-block
// preprocessing regrid (R7).
// R9: the aggs are DIVERGENT-LANE-bound (~1 lane/cy/CU: fp32->fp16 at
// fixed lane count bought only 13%; request count is the invariant).
// Halve lanes: 16B lanes (float4 = 8 halfs). C=32: LG=4 (was 8);
// C=16: LG=2 (was 4). EPI=8 -> dup overhead 14% (was 52%). Node tiling
// re-split: K4/K5 64 nodes/block, K2/K3/K6 128.

#define NN    165888            // total nodes = 2048*81
#define NBAT  2048
#define EPER  1620
#define NEDGE (NBAT * EPER)     // 3,317,760
#define ETOT  (NEDGE + NN)      // 3,483,648 (with self loops)
#define NBKT  648               // buckets of 256 nodes (dst>>8)
#define NBLK  512               // edge-pass blocks, 4 batches each
#define SCATE (4 * EPER)        // 6480 edges per scat block
#define SLICE 20736             // NN/8 (XCD swizzle for node-parallel kernels)
#define BCAP  6144              // LDS pairs cache per bucket (mean 5120)

// ---------------- block-wide exclusive scan (256 threads) ----------------

__device__ inline void blk_scan256(int val, int& excl, int& total, int* sw) {
  int lane = threadIdx.x & 63, w = threadIdx.x >> 6;
  int x = val;
#pragma unroll
  for (int off = 1; off < 64; off <<= 1) {
    int y = __shfl_up(x, off);
    if (lane >= off) x += y;
  }
  if (lane == 63) sw[w] = x;
  __syncthreads();
  int woff = 0;
  if (w > 0) woff = sw[0];
  if (w > 1) woff += sw[1];
  if (w > 2) woff += sw[2];
  total = sw[0] + sw[1] + sw[2] + sw[3];
  excl = woff + x - val;
}

// Exclusive prefix of btot[648] into LDS pb[648] (3 elements/thread, 648=3*216).
__device__ inline void pbase_scan(const int* __restrict__ btot, int* pb, int* sw) {
  int t = threadIdx.x;
  int e0 = 0, e1 = 0, e2 = 0, s = 0;
  if (t < 216) {
    e0 = btot[3 * t]; e1 = btot[3 * t + 1]; e2 = btot[3 * t + 2];
    s = e0 + e1 + e2;
  }
  int excl, tot;
  blk_scan256(s, excl, tot, sw);
  if (t < 216) {
    pb[3 * t]     = excl;
    pb[3 * t + 1] = excl + e0;
    pb[3 * t + 2] = excl + e0 + e1;
  }
  __syncthreads();
}

// ---------------- preprocessing ----------------

__global__ __launch_bounds__(256) void k_count(const int* __restrict__ ei,
                                               int* __restrict__ counts) {
  __shared__ int cnt[NBKT];
  int t = threadIdx.x;
  for (int k = t; k < NBKT; k += 256) cnt[k] = 0;
  __syncthreads();
  int b0 = blockIdx.x * 4;
  for (int b = b0; b < b0 + 4; ++b) {
    const int* dstp = ei + (size_t)b * (2 * EPER) + EPER;
    for (int e = t; e < EPER; e += 256) atomicAdd(&cnt[dstp[e] >> 8], 1);
  }
  __syncthreads();
  for (int k = t; k < NBKT; k += 256) counts[blockIdx.x * NBKT + k] = cnt[k];
}

__global__ __launch_bounds__(256) void k_scan(const int* __restrict__ counts,
                                              int* __restrict__ basesT,
                                              int* __restrict__ btot) {
  int bkt = blockIdx.x, t = threadIdx.x;
  int a = counts[(2 * t)     * NBKT + bkt];
  int b = counts[(2 * t + 1) * NBKT + bkt];
  __shared__ int sw[4];
  int excl, tot;
  blk_scan256(a + b, excl, tot, sw);
  basesT[bkt * NBLK + 2 * t]     = excl;
  basesT[bkt * NBLK + 2 * t + 1] = excl + a;
  if (t == 255) btot[bkt] = tot;
}

// R8 k_scat: LDS bucket-sort then coalesced flush.
__global__ __launch_bounds__(256) void k_scat(const int* __restrict__ ei,
                                              const int* __restrict__ basesT,
                                              const int* __restrict__ btot,
                                              unsigned int* __restrict__ pairs) {
  __shared__ int pb[NBKT];
  __shared__ int sw[4];
  __shared__ int cnt[NBKT];                    // histogram, then local offsets
  __shared__ int lcur[NBKT];                   // placement cursors
  __shared__ int gdst[NBKT];                   // global base - local base
  __shared__ unsigned int sorted[SCATE];       // 25.9 KB
  __shared__ unsigned short sbkt[SCATE];       // 13 KB
  int t = threadIdx.x;
  for (int k = t; k < NBKT; k += 256) cnt[k] = 0;
  pbase_scan(btot, pb, sw);                    // trailing sync orders cnt zero
  int b0 = blockIdx.x * 4;
  // pass 1: histogram
  for (int b = b0; b < b0 + 4; ++b) {
    const int* dstp = ei + (size_t)b * (2 * EPER) + EPER;
    for (int e = t; e < EPER; e += 256) atomicAdd(&cnt[dstp[e] >> 8], 1);
  }
  __syncthreads();
  // local exclusive scan of cnt (3/thread), write back in place
  {
    int e0 = 0, e1 = 0, e2 = 0, s = 0;
    if (t < 216) {
      e0 = cnt[3 * t]; e1 = cnt[3 * t + 1]; e2 = cnt[3 * t + 2];
      s = e0 + e1 + e2;
    }
    int excl, tot;
    blk_scan256(s, excl, tot, sw);             // internal barrier orders reads
    if (t < 216) {
      cnt[3 * t]     = excl;
      cnt[3 * t + 1] = excl + e0;
      cnt[3 * t + 2] = excl + e0 + e1;
    }
  }
  __syncthreads();
  for (int k = t; k < NBKT; k += 256) {
    int loc = cnt[k];
    gdst[k] = pb[k] + basesT[k * NBLK + blockIdx.x] - loc;
    lcur[k] = loc;
  }
  __syncthreads();
  // pass 2: re-read edges (L2-hot), place into sorted LDS
  for (int b = b0; b < b0 + 4; ++b) {
    const int* srcp = ei + (size_t)b * (2 * EPER);
    const int* dstp = srcp + EPER;
    for (int e = t; e < EPER; e += 256) {
      int d = dstp[e];
      int bk = d >> 8;
      int pos = atomicAdd(&lcur[bk], 1);
      sorted[pos] = (unsigned int)srcp[e] | ((unsigned int)(d & 255) << 24);
      sbkt[pos]   = (unsigned short)bk;
    }
  }
  __syncthreads();
  // flush: sorted stream -> per-bucket contiguous global runs
  for (int k = t; k < SCATE; k += 256)
    pairs[gdst[sbkt[k]] + k] = sorted[k];
}

// k_build (+fused K1 gemm): CSR rows for one bucket (pairs cached in LDS,
// single global read), dinv, self loops, then g0 = dinv ⊙ (x @ W1) -> fp16.
__global__ __launch_bounds__(256) void k_build(const unsigned int* __restrict__ pairs,
                                               const int* __restrict__ btot,
                                               const float* __restrict__ x,
                                               const float* __restrict__ W1,
                                               int* __restrict__ row_start,
                                               int* __restrict__ row_end,
                                               float* __restrict__ dinv,
                                               int* __restrict__ csr,
                                               __half* __restrict__ g0) {
  __shared__ int pb[NBKT];
  __shared__ int sw[4];
  __shared__ int cnt[256];
  __shared__ unsigned int sp[BCAP];
  __shared__ float sW[160];
  int bkt = blockIdx.x, t = threadIdx.x;
  cnt[t] = 0;
  if (t < 160) sW[t] = W1[t];
  pbase_scan(btot, pb, sw);                     // trailing sync orders cnt/sW too
  int p0 = pb[bkt];
  int n  = btot[bkt];
  for (int k = t; k < n; k += 256) {
    unsigned int pr = pairs[p0 + k];
    if (k < BCAP) sp[k] = pr;
    atomicAdd(&cnt[pr >> 24], 1);
  }
  __syncthreads();
  int indeg = cnt[t];
  int excl, tot;
  blk_scan256(indeg, excl, tot, sw);
  int csrbase = p0 + bkt * 256;                 // + self-loop slots of prior buckets
  int rs   = csrbase + excl + t;
  int node = bkt * 256 + t;
  int d    = indeg + 1;
  float di = rsqrtf((float)d);
  row_start[node] = rs;
  row_end[node]   = rs + d;
  dinv[node] = di;
  csr[rs] = node;                               // self loop
  __syncthreads();
  cnt[t] = rs + 1;                              // reuse as cursors
  __syncthreads();
  for (int k = t; k < n; k += 256) {
    unsigned int pr = (k < BCAP) ? sp[k] : pairs[p0 + k];
    int pos = atomicAdd(&cnt[pr >> 24], 1);
    csr[pos] = (int)(pr & 0x00FFFFFFu);
  }
  // fused K1: g0 = dinv ⊙ (x @ W1)  (10 -> 16), packed fp16
  float r[10];
#pragma unroll
  for (int k = 0; k < 10; ++k) r[k] = x[(size_t)node * 10 + k];
  float acc[16];
#pragma unroll
  for (int j = 0; j < 16; ++j) acc[j] = 0.0f;
#pragma unroll
  for (int k = 0; k < 10; ++k) {
    float rv = r[k];
#pragma unroll
    for (int j = 0; j < 16; ++j) acc[j] = fmaf(rv, sW[k * 16 + j], acc[j]);
  }
  __half* op = g0 + (size_t)node * 16;
  union { int4 v; __half2 h[4]; } pk;
#pragma unroll
  for (int half8 = 0; half8 < 2; ++half8) {
#pragma unroll
    for (int j = 0; j < 4; ++j)
      pk.h[j] = __floats2half2_rn(acc[half8 * 8 + 2 * j] * di,
                                  acc[half8 * 8 + 2 * j + 1] * di);
    *(int4*)(op + half8 * 8) = pk.v;
  }
}

// ------------- branchless agg core, 16B lanes (R9) -------------
// LG = C/8 lanes per row; each lane loads float4 = 8 halfs of its edge's
// row. Clamped slots read row re-1; subtract dups*v_last. Accumulates
// 8 fp32 (cols q*8 .. q*8+7).

template <int C, int EPI>
__device__ inline void agg_core_h16(const __half* __restrict__ g,
                                    const int* __restrict__ csr,
                                    int rs, int re, int q, int gl,
                                    float4& outLo, float4& outHi) {
  constexpr int LG = C / 8;
  float4 aLo = make_float4(0.f, 0.f, 0.f, 0.f);
  float4 aHi = make_float4(0.f, 0.f, 0.f, 0.f);
  const __half* gq = g + (size_t)q * 8;
  int iters = 0;
  for (int p = rs; p < re; p += EPI) {
    ++iters;
    int m[EPI / LG];
#pragma unroll
    for (int u = 0; u < EPI / LG; ++u) {
      int idx = p + u * LG + q;
      m[u] = csr[idx < re ? idx : re - 1];
    }
    float4 v[EPI];
#pragma unroll
    for (int j = 0; j < EPI; ++j) {
      int s = __shfl(m[j / LG], gl + (j % LG));
      v[j] = *(const float4*)(gq + (size_t)s * C);
    }
#pragma unroll
    for (int j = 0; j < EPI; ++j) {
      const __half2* hp = (const __half2*)&v[j];
      float2 f0 = __half22float2(hp[0]);
      float2 f1 = __half22float2(hp[1]);
      float2 f2 = __half22float2(hp[2]);
      float2 f3 = __half22float2(hp[3]);
      aLo.x += f0.x; aLo.y += f0.y; aLo.z += f1.x; aLo.w += f1.y;
      aHi.x += f2.x; aHi.y += f2.y; aHi.z += f3.x; aHi.w += f3.y;
    }
  }
  float dups = (float)(iters * EPI - (re - rs));
  int slast = csr[re - 1];
  float4 vl = *(const float4*)(gq + (size_t)slast * C);
  const __half2* hp = (const __half2*)&vl;
  float2 f0 = __half22float2(hp[0]);
  float2 f1 = __half22float2(hp[1]);
  float2 f2 = __half22float2(hp[2]);
  float2 f3 = __half22float2(hp[3]);
  aLo.x = fmaf(-dups, f0.x, aLo.x); aLo.y = fmaf(-dups, f0.y, aLo.y);
  aLo.z = fmaf(-dups, f1.x, aLo.z); aLo.w = fmaf(-dups, f1.y, aLo.w);
  aHi.x = fmaf(-dups, f2.x, aHi.x); aHi.y = fmaf(-dups, f2.y, aHi.y);
  aHi.z = fmaf(-dups, f3.x, aHi.z); aHi.w = fmaf(-dups, f3.y, aHi.w);
  outLo = aLo; outHi = aHi;
}

// ---------------- K2: g1 = dinv ⊙ relu(dinv·Σg0 + b1)  (C=16, LG=2) ----------

__global__ __launch_bounds__(256) void k_agg_ep16(const __half* __restrict__ g,
                                                  const int* __restrict__ row_start,
                                                  const int* __restrict__ row_end,
                                                  const int* __restrict__ csr,
                                                  const float* __restrict__ dinv,
                                                  const float* __restrict__ bias,
                                                  __half* __restrict__ out) {
  constexpr int NPB = 128, SPB = SLICE / NPB;
  int t  = threadIdx.x;
  int q  = t & 1;
  int bi = blockIdx.x;
  int vb = (bi & 7) * SPB + (bi >> 3);
  int i  = vb * NPB + t / 2;
  int gl = (t & 63) & ~1;
  float4 aLo, aHi;
  agg_core_h16<16, 8>(g, csr, row_start[i], row_end[i], q, gl, aLo, aHi);
  float di = dinv[i];
  const float* bp = bias + q * 8;
  float4 b0 = *(const float4*)bp;
  float4 b1 = *(const float4*)(bp + 4);
  aLo.x = fmaxf(fmaf(di, aLo.x, b0.x), 0.f) * di;
  aLo.y = fmaxf(fmaf(di, aLo.y, b0.y), 0.f) * di;
  aLo.z = fmaxf(fmaf(di, aLo.z, b0.z), 0.f) * di;
  aLo.w = fmaxf(fmaf(di, aLo.w, b0.w), 0.f) * di;
  aHi.x = fmaxf(fmaf(di, aHi.x, b1.x), 0.f) * di;
  aHi.y = fmaxf(fmaf(di, aHi.y, b1.y), 0.f) * di;
  aHi.z = fmaxf(fmaf(di, aHi.z, b1.z), 0.f) * di;
  aHi.w = fmaxf(fmaf(di, aHi.w, b1.w), 0.f) * di;
  union { int4 v; __half2 h[4]; } pk;
  pk.h[0] = __floats2half2_rn(aLo.x, aLo.y);
  pk.h[1] = __floats2half2_rn(aLo.z, aLo.w);
  pk.h[2] = __floats2half2_rn(aHi.x, aHi.y);
  pk.h[3] = __floats2half2_rn(aHi.z, aHi.w);
  *(int4*)(out + (size_t)i * 16 + q * 8) = pk.v;
}

// -- K3: a2 = dinv·Σg1 ; g2 = dinv ⊙ relu(a2@W2+b2) (16->32), LG=2 ------------

__global__ __launch_bounds__(256) void k_agg_g2(const __half* __restrict__ g,
                                                const int* __restrict__ row_start,
                                                const int* __restrict__ row_end,
                                                const int* __restrict__ csr,
                                                const float* __restrict__ dinv,
                                                const float* __restrict__ W2,
                                                const float* __restrict__ b2,
                                                __half* __restrict__ out) {
  constexpr int CI = 16, CO = 32, NPB = 128, SPB = SLICE / NPB, RP = 17;
  __shared__ float sW[CI * CO];
  __shared__ float sB[CO];
  __shared__ float rows[NPB * RP];
  __shared__ float sdi[NPB];
  int t = threadIdx.x;
  for (int k = t; k < CI * CO; k += 256) sW[k] = W2[k];
  if (t < CO) sB[t] = b2[t];
  int bi = blockIdx.x;
  int vb = (bi & 7) * SPB + (bi >> 3);
  int nbase = vb * NPB;
  int q = t & 1, nl = t / 2;
  int i = nbase + nl;
  int gl = (t & 63) & ~1;
  float4 aLo, aHi;
  agg_core_h16<16, 8>(g, csr, row_start[i], row_end[i], q, gl, aLo, aHi);
  float di = dinv[i];
  aLo.x *= di; aLo.y *= di; aLo.z *= di; aLo.w *= di;
  aHi.x *= di; aHi.y *= di; aHi.z *= di; aHi.w *= di;
  *(float4*)&rows[nl * RP + q * 8]     = aLo;
  *(float4*)&rows[nl * RP + q * 8 + 4] = aHi;
  if (q == 0) sdi[nl] = di;
  __syncthreads();
  int n2 = t >> 1, c = t & 1;                  // 2 threads/node, 16 outs each
  float o[16];
#pragma unroll
  for (int j = 0; j < 16; ++j) o[j] = sB[c * 16 + j];
  const float* row = &rows[n2 * RP];
#pragma unroll
  for (int k = 0; k < CI; ++k) {
    float rv = row[k];
#pragma unroll
    for (int j = 0; j < 16; ++j) o[j] = fmaf(rv, sW[k * CO + c * 16 + j], o[j]);
  }
  float d2 = sdi[n2];
#pragma unroll
  for (int j = 0; j < 16; ++j) o[j] = fmaxf(o[j], 0.f) * d2;
  __half* op = out + (size_t)(nbase + n2) * 32 + c * 16;
  union { int4 v; __half2 h[4]; } pk;
#pragma unroll
  for (int half8 = 0; half8 < 2; ++half8) {
#pragma unroll
    for (int j = 0; j < 4; ++j)
      pk.h[j] = __floats2half2_rn(o[half8 * 8 + 2 * j], o[half8 * 8 + 2 * j + 1]);
    *(int4*)(op + half8 * 8) = pk.v;
  }
}

// ---- K4: a3 = dinv·Σg2 ; h3 = relu(a3@W3+b3); g4 = dinv⊙(h3@W4) (32->64->32) --
// LG=4 (16B lanes), 64 nodes/block; dense stages 4 threads/node.
// LDS ~42KB -> 3 blocks/CU (accepted: lane work halved).

__global__ __launch_bounds__(256) void k_agg_g34(const __half* __restrict__ g,
                                                 const int* __restrict__ row_start,
                                                 const int* __restrict__ row_end,
                                                 const int* __restrict__ csr,
                                                 const float* __restrict__ dinv,
                                                 const float* __restrict__ W3,
                                                 const float* __restrict__ b3,
                                                 const float* __restrict__ W4,
                                                 __half* __restrict__ out) {
  constexpr int NPB = 64, SPB = SLICE / NPB, RP = 33, HP = 65;
  __shared__ float sW3[32 * 64];
  __shared__ float sW4[64 * 32];
  __shared__ float sB3[64];
  __shared__ float rows[NPB * RP];
  __shared__ float hrows[NPB * HP];
  __shared__ float sdi[NPB];
  int t = threadIdx.x;
  for (int k = t; k < 2048; k += 256) { sW3[k] = W3[k]; sW4[k] = W4[k]; }
  if (t < 64) sB3[t] = b3[t];
  int bi = blockIdx.x;
  int vb = (bi & 7) * SPB + (bi >> 3);
  int nbase = vb * NPB;
  int q = t & 3, nl = t / 4;
  int i = nbase + nl;
  int gl = (t & 63) & ~3;
  float4 aLo, aHi;
  agg_core_h16<32, 8>(g, csr, row_start[i], row_end[i], q, gl, aLo, aHi);
  float di = dinv[i];
  aLo.x *= di; aLo.y *= di; aLo.z *= di; aLo.w *= di;
  aHi.x *= di; aHi.y *= di; aHi.z *= di; aHi.w *= di;
  *(float4*)&rows[nl * RP + q * 8]     = aLo;
  *(float4*)&rows[nl * RP + q * 8 + 4] = aHi;
  if (q == 0) sdi[nl] = di;
  __syncthreads();
  int n2 = t >> 2, c = t & 3;                  // 4 threads/node
  {                                            // stage 1: 16 of 64 h each
    float o[16];
#pragma unroll
    for (int j = 0; j < 16; ++j) o[j] = sB3[c * 16 + j];
    const float* row = &rows[n2 * RP];
#pragma unroll
    for (int k = 0; k < 32; ++k) {
      float rv = row[k];
#pragma unroll
      for (int j = 0; j < 16; ++j) o[j] = fmaf(rv, sW3[k * 64 + c * 16 + j], o[j]);
    }
    float* hp = &hrows[n2 * HP + c * 16];
#pragma unroll
    for (int j = 0; j < 16; ++j) hp[j] = fmaxf(o[j], 0.f);
  }
  __syncthreads();
  {                                            // stage 2: 8 of 32 outs each
    float o[8] = {0.f, 0.f, 0.f, 0.f, 0.f, 0.f, 0.f, 0.f};
    const float* hp = &hrows[n2 * HP];
#pragma unroll
    for (int k = 0; k < 64; ++k) {
      float hv = hp[k];
#pragma unroll
      for (int j = 0; j < 8; ++j) o[j] = fmaf(hv, sW4[k * 32 + c * 8 + j], o[j]);
    }
    float d2 = sdi[n2];
    union { int4 v; __half2 h[4]; } pk;
#pragma unroll
    for (int j = 0; j < 4; ++j)
      pk.h[j] = __floats2half2_rn(o[2 * j] * d2, o[2 * j + 1] * d2);
    *(int4*)(out + (size_t)(nbase + n2) * 32 + c * 8) = pk.v;
  }
}

// ---- K5: h4 = relu(dinv·Σg4 + b4); g5 = dinv⊙(h4@W5)  (32->16), LG=4 --------

__global__ __launch_bounds__(256) void k_agg_g5(const __half* __restrict__ g,
                                                const int* __restrict__ row_start,
                                                const int* __restrict__ row_end,
                                                const int* __restrict__ csr,
                                                const float* __restrict__ dinv,
                                                const float* __restrict__ b4,
                                                const float* __restrict__ W5,
                                                __half* __restrict__ out) {
  constexpr int NPB = 64, SPB = SLICE / NPB, RP = 33;
  __shared__ float sW[32 * 16];
  __shared__ float rows[NPB * RP];
  __shared__ float sdi[NPB];
  int t = threadIdx.x;
  for (int k = t; k < 512; k += 256) sW[k] = W5[k];
  int bi = blockIdx.x;
  int vb = (bi & 7) * SPB + (bi >> 3);
  int nbase = vb * NPB;
  int q = t & 3, nl = t / 4;
  int i = nbase + nl;
  int gl = (t & 63) & ~3;
  float4 aLo, aHi;
  agg_core_h16<32, 8>(g, csr, row_start[i], row_end[i], q, gl, aLo, aHi);
  float di = dinv[i];
  const float* bp = b4 + q * 8;
  float4 b0 = *(const float4*)bp;
  float4 b1 = *(const float4*)(bp + 4);
  aLo.x = fmaxf(fmaf(di, aLo.x, b0.x), 0.f);
  aLo.y = fmaxf(fmaf(di, aLo.y, b0.y), 0.f);
  aLo.z = fmaxf(fmaf(di, aLo.z, b0.z), 0.f);
  aLo.w = fmaxf(fmaf(di, aLo.w, b0.w), 0.f);
  aHi.x = fmaxf(fmaf(di, aHi.x, b1.x), 0.f);
  aHi.y = fmaxf(fmaf(di, aHi.y, b1.y), 0.f);
  aHi.z = fmaxf(fmaf(di, aHi.z, b1.z), 0.f);
  aHi.w = fmaxf(fmaf(di, aHi.w, b1.w), 0.f);
  *(float4*)&rows[nl * RP + q * 8]     = aLo;
  *(float4*)&rows[nl * RP + q * 8 + 4] = aHi;
  if (q == 0) sdi[nl] = di;
  __syncthreads();
  int n2 = t >> 2, c = t & 3;                  // 4 threads/node, 4 of 16 outs
  float o[4] = {0.f, 0.f, 0.f, 0.f};
  const float* row = &rows[n2 * RP];
#pragma unroll
  for (int k = 0; k < 32; ++k) {
    float rv = row[k];
#pragma unroll
    for (int j = 0; j < 4; ++j) o[j] = fmaf(rv, sW[k * 16 + c * 4 + j], o[j]);
  }
  float d2 = sdi[n2];
  union { int2 v; __half2 h[2]; } pk;
  pk.h[0] = __floats2half2_rn(o[0] * d2, o[1] * d2);
  pk.h[1] = __floats2half2_rn(o[2] * d2, o[3] * d2);
  *(int2*)(out + (size_t)(nbase + n2) * 16 + c * 4) = pk.v;
}

// ---- K6: h5 = relu(dinv·Σg5 + b5); out = relu(h5@fW1+fb1)@fW2+fb2, LG=2 -----

__global__ __launch_bounds__(256) void k_agg_mlp(const __half* __restrict__ g,
                                                 const int* __restrict__ row_start,
                                                 const int* __restrict__ row_end,
                                                 const int* __restrict__ csr,
                                                 const float* __restrict__ dinv,
                                                 const float* __restrict__ b5,
                                                 const float* __restrict__ fW1,
                                                 const float* __restrict__ fb1,
                                                 const float* __restrict__ fW2,
                                                 const float* __restrict__ fb2,
                                                 float* __restrict__ out) {
  constexpr int NPB = 128, SPB = SLICE / NPB, RP = 17;
  __shared__ float sW1[256], sW2[144], sB1[16], sB2[9];
  __shared__ float rows[NPB * RP];
  __shared__ float zrows[NPB * RP];
  __shared__ float ost[NPB * 9];
  int t = threadIdx.x;
  sW1[t] = fW1[t];
  if (t < 144) sW2[t] = fW2[t];
  if (t < 16)  sB1[t] = fb1[t];
  if (t < 9)   sB2[t] = fb2[t];
  int bi = blockIdx.x;
  int vb = (bi & 7) * SPB + (bi >> 3);
  int nbase = vb * NPB;
  int q = t & 1, nl = t / 2;
  int i = nbase + nl;
  int gl = (t & 63) & ~1;
  float4 aLo, aHi;
  agg_core_h16<16, 8>(g, csr, row_start[i], row_end[i], q, gl, aLo, aHi);
  float di = dinv[i];
  const float* bp = b5 + q * 8;
  float4 b0 = *(const float4*)bp;
  float4 b1 = *(const float4*)(bp + 4);
  aLo.x = fmaxf(fmaf(di, aLo.x, b0.x), 0.f);
  aLo.y = fmaxf(fmaf(di, aLo.y, b0.y), 0.f);
  aLo.z = fmaxf(fmaf(di, aLo.z, b0.z), 0.f);
  aLo.w = fmaxf(fmaf(di, aLo.w, b0.w), 0.f);
  aHi.x = fmaxf(fmaf(di, aHi.x, b1.x), 0.f);
  aHi.y = fmaxf(fmaf(di, aHi.y, b1.y), 0.f);
  aHi.z = fmaxf(fmaf(di, aHi.z, b1.z), 0.f);
  aHi.w = fmaxf(fmaf(di, aHi.w, b1.w), 0.f);
  *(float4*)&rows[nl * RP + q * 8]     = aLo;
  *(float4*)&rows[nl * RP + q * 8 + 4] = aHi;
  __syncthreads();
  int n2 = t >> 1, c = t & 1;                  // 2 threads/node
  {                                            // z = relu(h5@fW1+fb1), 8 each
    float o[8];
#pragma unroll
    for (int j = 0; j < 8; ++j) o[j] = sB1[c * 8 + j];
    const float* row = &rows[n2 * RP];
#pragma unroll
    for (int k = 0; k < 16; ++k) {
      float rv = row[k];
#pragma unroll
      for (int j = 0; j < 8; ++j) o[j] = fmaf(rv, sW1[k * 16 + c * 8 + j], o[j]);
    }
    float* zp = &zrows[n2 * RP + c * 8];
#pragma unroll
    for (int j = 0; j < 8; ++j) zp[j] = fmaxf(o[j], 0.f);
  }
  __syncthreads();
  {                                            // 9 outs: c=0 -> 0..4, c=1 -> 5..8
    const float* zp = &zrows[n2 * RP];
    if (c == 0) {
      float o[5];
#pragma unroll
      for (int j = 0; j < 5; ++j) o[j] = sB2[j];
#pragma unroll
      for (int k = 0; k < 16; ++k) {
        float zv = zp[k];
#pragma unroll
        for (int j = 0; j < 5; ++j) o[j] = fmaf(zv, sW2[k * 9 + j], o[j]);
      }
#pragma unroll
      for (int j = 0; j < 5; ++j) ost[n2 * 9 + j] = o[j];
    } else {
      float o[4];
#pragma unroll
      for (int j = 0; j < 4; ++j) o[j] = sB2[5 + j];
#pragma unroll
      for (int k = 0; k < 16; ++k) {
        float zv = zp[k];
#pragma unroll
        for (int j = 0; j < 4; ++j) o[j] = fmaf(zv, sW2[k * 9 + 5 + j], o[j]);
      }
#pragma unroll
      for (int j = 0; j < 4; ++j) ost[n2 * 9 + 5 + j] = o[j];
    }
  }
  __syncthreads();
  float* ob = out + (size_t)nbase * 9;
  for (int k = t; k < NPB * 9; k += 256) ob[k] = ost[k];
}

// ---------------- launch ----------------

extern "C" void kernel_launch(void* const* d_in, const int* in_sizes, int n_in,
                              void* d_out, int out_size, void* d_ws, size_t ws_size,
                              hipStream_t stream) {
  const float* x   = (const float*)d_in[0];
  const int*   ei  = (const int*)d_in[1];
  const float* W1  = (const float*)d_in[2];
  const float* b1  = (const float*)d_in[3];
  const float* W2  = (const float*)d_in[4];
  const float* b2  = (const float*)d_in[5];
  const float* W3  = (const float*)d_in[6];
  const float* b3  = (const float*)d_in[7];
  const float* W4  = (const float*)d_in[8];
  const float* b4  = (const float*)d_in[9];
  const float* W5  = (const float*)d_in[10];
  const float* b5  = (const float*)d_in[11];
  const float* fW1 = (const float*)d_in[12];
  const float* fb1 = (const float*)d_in[13];
  const float* fW2 = (const float*)d_in[14];
  const float* fb2 = (const float*)d_in[15];
  float* out = (float*)d_out;

  char* ws = (char*)d_ws;
  size_t off = 0;
  auto alloc = [&](size_t bytes) -> char* {
    char* p = ws + off;
    off += (bytes + 255) & ~(size_t)255;
    return p;
  };
  int*   counts  = (int*)  alloc((size_t)NBLK * NBKT * 4);
  int*   basesT  = (int*)  alloc((size_t)NBKT * NBLK * 4);
  int*   btot    = (int*)  alloc((size_t)NBKT * 4);
  unsigned int* pairs = (unsigned int*)alloc((size_t)NEDGE * 4);
  int*   rs_     = (int*)  alloc((size_t)NN * 4);
  int*   re_     = (int*)  alloc((size_t)NN * 4);
  float* dinv    = (float*)alloc((size_t)NN * 4);
  int*   csr     = (int*)  alloc((size_t)ETOT * 4);
  __half* H16a   = (__half*)alloc((size_t)NN * 16 * 2);   // g0, then g5
  __half* H16b   = (__half*)alloc((size_t)NN * 16 * 2);   // g1
  __half* H32a   = (__half*)alloc((size_t)NN * 32 * 2);   // g2
  __half* H32b   = (__half*)alloc((size_t)NN * 32 * 2);   // g4

  k_count<<<NBLK, 256, 0, stream>>>(ei, counts);
  k_scan <<<NBKT, 256, 0, stream>>>(counts, basesT, btot);
  k_scat <<<NBLK, 256, 0, stream>>>(ei, basesT, btot, pairs);
  // k_build + fused K1: csr/dinv/bounds + g0 = dinv⊙(x@W1) -> fp16
  k_build<<<NBKT, 256, 0, stream>>>(pairs, btot, x, W1, rs_, re_, dinv, csr, H16a);

  // K2: g1 = dinv⊙relu(dinv·Σg0 + b1) -> fp16
  k_agg_ep16<<<NN / 128, 256, 0, stream>>>(H16a, rs_, re_, csr, dinv, b1, H16b);
  // K3: g2 = dinv⊙relu((dinv·Σg1)@W2 + b2) -> fp16
  k_agg_g2<<<NN / 128, 256, 0, stream>>>(H16b, rs_, re_, csr, dinv, W2, b2, H32a);
  // K4: g4 = dinv⊙(relu((dinv·Σg2)@W3+b3)@W4) -> fp16
  k_agg_g34<<<NN / 64, 256, 0, stream>>>(H32a, rs_, re_, csr, dinv, W3, b3, W4, H32b);
  // K5: g5 = dinv⊙(relu(dinv·Σg4 + b4)@W5) -> fp16 (reuses H16a, g0 dead)
  k_agg_g5<<<NN / 64, 256, 0, stream>>>(H32b, rs_, re_, csr, dinv, b4, W5, H16a);
  // K6: head MLP on h5 = relu(dinv·Σg5 + b5), fp32 out
  k_agg_mlp<<<NN / 128, 256, 0, stream>>>(H16a, rs_, re_, csr, dinv, b5,
                                          fW1, fb1, fW2, fb2, out);
}

// Round 11
// 364.232 us; speedup vs baseline: 1.1346x; 1.1346x over previous
//
#include <hip/hip_runtime.h>
#include <hip/hip_fp16.h>

// Sudoku GNN: 5x GCNConv (shared graph) + 2-layer MLP head.
// CSR via two-level bucket sort (no global atomics). Weight-free CSR
// (dinv factored into producers/consumers). Pull-based aggs fused with
// the following dense stage through LDS row staging.
// Confirmed levers: fp16 on all gathered arrays (R4/R5, 470->379us);
// k_scat LDS bucket-sort (R8, write-amp 5.3x -> ~1.5x, 396->367us).
// Dead levers: occupancy>47% for the random gather (R1-R3: more waves
// LOWERED achieved BW); 256B in-flight bursts (R6); 2048-block
// preprocessing regrid (R7); fewer/wider lanes (R9: constant bytes,
// half the lanes -> no change); fp8 gathered arrays (R10: absmax
// 7.3e-4 > 9.9e-6 threshold — outputs compared in bf16, fp16 rounds
// away but fp8 doesn't. Precision floor = fp16).
// Model (fits R0-R10): agg time = FETCH / ~2.4 TB/s beyond-L2 random-
// gather service rate. At fp16 working sets (10.6MB C=32, 5.3MB C=16
// vs 4MB per-XCD L2) FETCH is compulsory -> this is the roofline.

#define NN    165888            // total nodes = 2048*81
#define NBAT  2048
#define EPER  1620
#define NEDGE (NBAT * EPER)     // 3,317,760
#define ETOT  (NEDGE + NN)      // 3,483,648 (with self loops)
#define NBKT  648               // buckets of 256 nodes (dst>>8)
#define NBLK  512               // edge-pass blocks, 4 batches each
#define SCATE (4 * EPER)        // 6480 edges per scat block
#define SLICE 20736             // NN/8 (XCD swizzle for node-parallel kernels)
#define BCAP  6144              // LDS pairs cache per bucket (mean 5120)

// ---------------- block-wide exclusive scan (256 threads) ----------------

__device__ inline void blk_scan256(int val, int& excl, int& total, int* sw) {
  int lane = threadIdx.x & 63, w = threadIdx.x >> 6;
  int x = val;
#pragma unroll
  for (int off = 1; off < 64; off <<= 1) {
    int y = __shfl_up(x, off);
    if (lane >= off) x += y;
  }
  if (lane == 63) sw[w] = x;
  __syncthreads();
  int woff = 0;
  if (w > 0) woff = sw[0];
  if (w > 1) woff += sw[1];
  if (w > 2) woff += sw[2];
  total = sw[0] + sw[1] + sw[2] + sw[3];
  excl = woff + x - val;
}

// Exclusive prefix of btot[648] into LDS pb[648] (3 elements/thread, 648=3*216).
__device__ inline void pbase_scan(const int* __restrict__ btot, int* pb, int* sw) {
  int t = threadIdx.x;
  int e0 = 0, e1 = 0, e2 = 0, s = 0;
  if (t < 216) {
    e0 = btot[3 * t]; e1 = btot[3 * t + 1]; e2 = btot[3 * t + 2];
    s = e0 + e1 + e2;
  }
  int excl, tot;
  blk_scan256(s, excl, tot, sw);
  if (t < 216) {
    pb[3 * t]     = excl;
    pb[3 * t + 1] = excl + e0;
    pb[3 * t + 2] = excl + e0 + e1;
  }
  __syncthreads();
}

// ---------------- preprocessing ----------------

__global__ __launch_bounds__(256) void k_count(const int* __restrict__ ei,
                                               int* __restrict__ counts) {
  __shared__ int cnt[NBKT];
  int t = threadIdx.x;
  for (int k = t; k < NBKT; k += 256) cnt[k] = 0;
  __syncthreads();
  int b0 = blockIdx.x * 4;
  for (int b = b0; b < b0 + 4; ++b) {
    const int* dstp = ei + (size_t)b * (2 * EPER) + EPER;
    for (int e = t; e < EPER; e += 256) atomicAdd(&cnt[dstp[e] >> 8], 1);
  }
  __syncthreads();
  for (int k = t; k < NBKT; k += 256) counts[blockIdx.x * NBKT + k] = cnt[k];
}

__global__ __launch_bounds__(256) void k_scan(const int* __restrict__ counts,
                                              int* __restrict__ basesT,
                                              int* __restrict__ btot) {
  int bkt = blockIdx.x, t = threadIdx.x;
  int a = counts[(2 * t)     * NBKT + bkt];
  int b = counts[(2 * t + 1) * NBKT + bkt];
  __shared__ int sw[4];
  int excl, tot;
  blk_scan256(a + b, excl, tot, sw);
  basesT[bkt * NBLK + 2 * t]     = excl;
  basesT[bkt * NBLK + 2 * t + 1] = excl + a;
  if (t == 255) btot[bkt] = tot;
}

// R8 k_scat: LDS bucket-sort then coalesced flush.
__global__ __launch_bounds__(256) void k_scat(const int* __restrict__ ei,
                                              const int* __restrict__ basesT,
                                              const int* __restrict__ btot,
                                              unsigned int* __restrict__ pairs) {
  __shared__ int pb[NBKT];
  __shared__ int sw[4];
  __shared__ int cnt[NBKT];                    // histogram, then local offsets
  __shared__ int lcur[NBKT];                   // placement cursors
  __shared__ int gdst[NBKT];                   // global base - local base
  __shared__ unsigned int sorted[SCATE];       // 25.9 KB
  __shared__ unsigned short sbkt[SCATE];       // 13 KB
  int t = threadIdx.x;
  for (int k = t; k < NBKT; k += 256) cnt[k] = 0;
  pbase_scan(btot, pb, sw);                    // trailing sync orders cnt zero
  int b0 = blockIdx.x * 4;
  // pass 1: histogram
  for (int b = b0; b < b0 + 4; ++b) {
    const int* dstp = ei + (size_t)b * (2 * EPER) + EPER;
    for (int e = t; e < EPER; e += 256) atomicAdd(&cnt[dstp[e] >> 8], 1);
  }
  __syncthreads();
  // local exclusive scan of cnt (3/thread), write back in place
  {
    int e0 = 0, e1 = 0, e2 = 0, s = 0;
    if (t < 216) {
      e0 = cnt[3 * t]; e1 = cnt[3 * t + 1]; e2 = cnt[3 * t + 2];
      s = e0 + e1 + e2;
    }
    int excl, tot;
    blk_scan256(s, excl, tot, sw);             // internal barrier orders reads
    if (t < 216) {
      cnt[3 * t]     = excl;
      cnt[3 * t + 1] = excl + e0;
      cnt[3 * t + 2] = excl + e0 + e1;
    }
  }
  __syncthreads();
  for (int k = t; k < NBKT; k += 256) {
    int loc = cnt[k];
    gdst[k] = pb[k] + basesT[k * NBLK + blockIdx.x] - loc;
    lcur[k] = loc;
  }
  __syncthreads();
  // pass 2: re-read edges (L2-hot), place into sorted LDS
  for (int b = b0; b < b0 + 4; ++b) {
    const int* srcp = ei + (size_t)b * (2 * EPER);
    const int* dstp = srcp + EPER;
    for (int e = t; e < EPER; e += 256) {
      int d = dstp[e];
      int bk = d >> 8;
      int pos = atomicAdd(&lcur[bk], 1);
      sorted[pos] = (unsigned int)srcp[e] | ((unsigned int)(d & 255) << 24);
      sbkt[pos]   = (unsigned short)bk;
    }
  }
  __syncthreads();
  // flush: sorted stream -> per-bucket contiguous global runs
  for (int k = t; k < SCATE; k += 256)
    pairs[gdst[sbkt[k]] + k] = sorted[k];
}

// k_build (+fused K1 gemm): CSR rows for one bucket (pairs cached in LDS,
// single global read), dinv, self loops, then g0 = dinv ⊙ (x @ W1) -> fp16.
__global__ __launch_bounds__(256) void k_build(const unsigned int* __restrict__ pairs,
                                               const int* __restrict__ btot,
                                               const float* __restrict__ x,
                                               const float* __restrict__ W1,
                                               int* __restrict__ row_start,
                                               int* __restrict__ row_end,
                                               float* __restrict__ dinv,
                                               int* __restrict__ csr,
                                               __half* __restrict__ g0) {
  __shared__ int pb[NBKT];
  __shared__ int sw[4];
  __shared__ int cnt[256];
  __shared__ unsigned int sp[BCAP];
  __shared__ float sW[160];
  int bkt = blockIdx.x, t = threadIdx.x;
  cnt[t] = 0;
  if (t < 160) sW[t] = W1[t];
  pbase_scan(btot, pb, sw);                     // trailing sync orders cnt/sW too
  int p0 = pb[bkt];
  int n  = btot[bkt];
  for (int k = t; k < n; k += 256) {
    unsigned int pr = pairs[p0 + k];
    if (k < BCAP) sp[k] = pr;
    atomicAdd(&cnt[pr >> 24], 1);
  }
  __syncthreads();
  int indeg = cnt[t];
  int excl, tot;
  blk_scan256(indeg, excl, tot, sw);
  int csrbase = p0 + bkt * 256;                 // + self-loop slots of prior buckets
  int rs   = csrbase + excl + t;
  int node = bkt * 256 + t;
  int d    = indeg + 1;
  float di = rsqrtf((float)d);
  row_start[node] = rs;
  row_end[node]   = rs + d;
  dinv[node] = di;
  csr[rs] = node;                               // self loop
  __syncthreads();
  cnt[t] = rs + 1;                              // reuse as cursors
  __syncthreads();
  for (int k = t; k < n; k += 256) {
    unsigned int pr = (k < BCAP) ? sp[k] : pairs[p0 + k];
    int pos = atomicAdd(&cnt[pr >> 24], 1);
    csr[pos] = (int)(pr & 0x00FFFFFFu);
  }
  // fused K1: g0 = dinv ⊙ (x @ W1)  (10 -> 16), packed fp16
  float r[10];
#pragma unroll
  for (int k = 0; k < 10; ++k) r[k] = x[(size_t)node * 10 + k];
  float acc[16];
#pragma unroll
  for (int j = 0; j < 16; ++j) acc[j] = 0.0f;
#pragma unroll
  for (int k = 0; k < 10; ++k) {
    float rv = r[k];
#pragma unroll
    for (int j = 0; j < 16; ++j) acc[j] = fmaf(rv, sW[k * 16 + j], acc[j]);
  }
  __half* op = g0 + (size_t)node * 16;
  union { int4 v; __half2 h[4]; } pk;
#pragma unroll
  for (int half8 = 0; half8 < 2; ++half8) {
#pragma unroll
    for (int j = 0; j < 4; ++j)
      pk.h[j] = __floats2half2_rn(acc[half8 * 8 + 2 * j] * di,
                                  acc[half8 * 8 + 2 * j + 1] * di);
    *(int4*)(op + half8 * 8) = pk.v;
  }
}

// ------------- branchless agg core: EPI gathers in flight -------------
// Clamped slots all read row re-1; sum unweighted, subtract dups*v_last.
// fp16 rows (C halfs = 2C bytes): LG=C/4 lanes/node, each lane loads
// float2 = 4 halfs, unpacks, accumulates fp32.

template <int C, int EPI>
__device__ inline float4 agg_core_h(const __half* __restrict__ g,
                                    const int* __restrict__ csr,
                                    int rs, int re, int q, int gl) {
  constexpr int LG = C / 4;
  float4 acc = make_float4(0.f, 0.f, 0.f, 0.f);
  const __half* gq = g + (size_t)q * 4;
  int iters = 0;
  for (int p = rs; p < re; p += EPI) {
    ++iters;
    int m[EPI / LG];
#pragma unroll
    for (int u = 0; u < EPI / LG; ++u) {
      int idx = p + u * LG + q;
      m[u] = csr[idx < re ? idx : re - 1];
    }
    float2 v[EPI];
#pragma unroll
    for (int j = 0; j < EPI; ++j) {
      int s = __shfl(m[j / LG], gl + (j % LG));
      v[j] = *(const float2*)(gq + (size_t)s * C);
    }
#pragma unroll
    for (int j = 0; j < EPI; ++j) {
      const __half2* hp = (const __half2*)&v[j];
      float2 lo = __half22float2(hp[0]);
      float2 hi = __half22float2(hp[1]);
      acc.x += lo.x; acc.y += lo.y; acc.z += hi.x; acc.w += hi.y;
    }
  }
  float dups = (float)(iters * EPI - (re - rs));
  int slast = csr[re - 1];
  float2 vl = *(const float2*)(gq + (size_t)slast * C);
  const __half2* hp = (const __half2*)&vl;
  float2 lo = __half22float2(hp[0]);
  float2 hi = __half22float2(hp[1]);
  acc.x = fmaf(-dups, lo.x, acc.x);
  acc.y = fmaf(-dups, lo.y, acc.y);
  acc.z = fmaf(-dups, hi.x, acc.z);
  acc.w = fmaf(-dups, hi.y, acc.w);
  return acc;
}

// ---------------- K2: g1 = dinv ⊙ relu(dinv·Σg0 + b1)  (C=16, fp16 io) -------

__global__ __launch_bounds__(256) void k_agg_ep16(const __half* __restrict__ g,
                                                  const int* __restrict__ row_start,
                                                  const int* __restrict__ row_end,
                                                  const int* __restrict__ csr,
                                                  const float* __restrict__ dinv,
                                                  const float* __restrict__ bias,
                                                  __half* __restrict__ out) {
  constexpr int LG = 4, NPB = 64, SPB = SLICE / NPB;
  int t  = threadIdx.x;
  int q  = t & (LG - 1);
  int bi = blockIdx.x;
  int vb = (bi & 7) * SPB + (bi >> 3);
  int i  = vb * NPB + t / LG;
  int gl = (t & 63) & ~(LG - 1);
  float4 acc = agg_core_h<16, 16>(g, csr, row_start[i], row_end[i], q, gl);
  float di = dinv[i];
  float4 bb = *(const float4*)(bias + q * 4);
  acc.x = fmaxf(fmaf(di, acc.x, bb.x), 0.f) * di;
  acc.y = fmaxf(fmaf(di, acc.y, bb.y), 0.f) * di;
  acc.z = fmaxf(fmaf(di, acc.z, bb.z), 0.f) * di;
  acc.w = fmaxf(fmaf(di, acc.w, bb.w), 0.f) * di;
  union { int2 v; __half2 h[2]; } pk;
  pk.h[0] = __floats2half2_rn(acc.x, acc.y);
  pk.h[1] = __floats2half2_rn(acc.z, acc.w);
  *(int2*)(out + (size_t)i * 16 + q * 4) = pk.v;
}

// -- K3: a2 = dinv·Σg1 ; g2 = dinv ⊙ relu(a2@W2+b2) (16->32), fp16 io ---------

__global__ __launch_bounds__(256) void k_agg_g2(const __half* __restrict__ g,
                                                const int* __restrict__ row_start,
                                                const int* __restrict__ row_end,
                                                const int* __restrict__ csr,
                                                const float* __restrict__ dinv,
                                                const float* __restrict__ W2,
                                                const float* __restrict__ b2,
                                                __half* __restrict__ out) {
  constexpr int CI = 16, CO = 32, LG = 4, NPB = 64, SPB = SLICE / NPB, RP = 20;
  __shared__ float sW[CI * CO];
  __shared__ float sB[CO];
  __shared__ float rows[NPB * RP];
  __shared__ float sdi[NPB];
  int t = threadIdx.x;
  for (int k = t; k < CI * CO; k += 256) sW[k] = W2[k];
  if (t < CO) sB[t] = b2[t];
  int bi = blockIdx.x;
  int vb = (bi & 7) * SPB + (bi >> 3);
  int nbase = vb * NPB;
  int q = t & (LG - 1), nl = t / LG;
  int i = nbase + nl;
  int gl = (t & 63) & ~(LG - 1);
  float4 acc = agg_core_h<16, 16>(g, csr, row_start[i], row_end[i], q, gl);
  float di = dinv[i];
  acc.x *= di; acc.y *= di; acc.z *= di; acc.w *= di;
  *(float4*)&rows[nl * RP + q * 4] = acc;
  if (q == 0) sdi[nl] = di;
  __syncthreads();
  int n2 = t >> 2, c = t & 3;                  // 4 threads/node, 8 outs each
  float o[8];
#pragma unroll
  for (int j = 0; j < 8; ++j) o[j] = sB[c * 8 + j];
  const float* row = &rows[n2 * RP];
#pragma unroll
  for (int k = 0; k < CI; ++k) {
    float rv = row[k];
#pragma unroll
    for (int j = 0; j < 8; ++j) o[j] = fmaf(rv, sW[k * CO + c * 8 + j], o[j]);
  }
  float d2 = sdi[n2];
#pragma unroll
  for (int j = 0; j < 8; ++j) o[j] = fmaxf(o[j], 0.f) * d2;
  union { int4 v; __half2 h[4]; } pk;
#pragma unroll
  for (int j = 0; j < 4; ++j) pk.h[j] = __floats2half2_rn(o[2 * j], o[2 * j + 1]);
  *(int4*)(out + (size_t)(nbase + n2) * 32 + c * 8) = pk.v;
}

// ---- K4: a3 = dinv·Σg2 ; h3 = relu(a3@W3+b3); g4 = dinv⊙(h3@W4) (32->64->32) --
// R0 structure exactly (both weights staged, 30KB LDS, no cross-barrier
// register liveness); fp16 in (g2) and out (g4). EPI=16 (confirmed R6).

__global__ __launch_bounds__(256) void k_agg_g34(const __half* __restrict__ g,
                                                 const int* __restrict__ row_start,
                                                 const int* __restrict__ row_end,
                                                 const int* __restrict__ csr,
                                                 const float* __restrict__ dinv,
                                                 const float* __restrict__ W3,
                                                 const float* __restrict__ b3,
                                                 const float* __restrict__ W4,
                                                 __half* __restrict__ out) {
  constexpr int LG = 8, NPB = 32, SPB = SLICE / NPB, RP = 36, HP = 68;
  __shared__ float sW3[32 * 64];
  __shared__ float sW4[64 * 32];
  __shared__ float sB3[64];
  __shared__ float rows[NPB * RP];
  __shared__ float hrows[NPB * HP];
  __shared__ float sdi[NPB];
  int t = threadIdx.x;
  for (int k = t; k < 2048; k += 256) { sW3[k] = W3[k]; sW4[k] = W4[k]; }
  if (t < 64) sB3[t] = b3[t];
  int bi = blockIdx.x;
  int vb = (bi & 7) * SPB + (bi >> 3);
  int nbase = vb * NPB;
  int q = t & (LG - 1), nl = t / LG;
  int i = nbase + nl;
  int gl = (t & 63) & ~(LG - 1);
  float4 acc = agg_core_h<32, 16>(g, csr, row_start[i], row_end[i], q, gl);
  float di = dinv[i];
  acc.x *= di; acc.y *= di; acc.z *= di; acc.w *= di;
  *(float4*)&rows[nl * RP + q * 4] = acc;
  if (q == 0) sdi[nl] = di;
  __syncthreads();
  int n2 = t >> 3, c = t & 7;                  // 8 threads/node
  {                                            // stage 1: 8 of 64 h each
    float o[8];
#pragma unroll
    for (int j = 0; j < 8; ++j) o[j] = sB3[c * 8 + j];
    const float* row = &rows[n2 * RP];
#pragma unroll
    for (int k = 0; k < 32; ++k) {
      float rv = row[k];
#pragma unroll
      for (int j = 0; j < 8; ++j) o[j] = fmaf(rv, sW3[k * 64 + c * 8 + j], o[j]);
    }
    float* hp = &hrows[n2 * HP + c * 8];
#pragma unroll
    for (int j = 0; j < 8; ++j) hp[j] = fmaxf(o[j], 0.f);
  }
  __syncthreads();
  {                                            // stage 2: 4 of 32 outs each
    float o[4] = {0.f, 0.f, 0.f, 0.f};
    const float* hp = &hrows[n2 * HP];
#pragma unroll
    for (int k = 0; k < 64; ++k) {
      float hv = hp[k];
#pragma unroll
      for (int j = 0; j < 4; ++j) o[j] = fmaf(hv, sW4[k * 32 + c * 4 + j], o[j]);
    }
    float d2 = sdi[n2];
#pragma unroll
    for (int j = 0; j < 4; ++j) o[j] *= d2;
    union { int2 v; __half2 h[2]; } pk;
    pk.h[0] = __floats2half2_rn(o[0], o[1]);
    pk.h[1] = __floats2half2_rn(o[2], o[3]);
    *(int2*)(out + (size_t)(nbase + n2) * 32 + c * 4) = pk.v;
  }
}

// ---- K5: h4 = relu(dinv·Σg4 + b4); g5 = dinv⊙(h4@W5)  (32->16), fp16 io ----
// EPI=16 (EPI32 regressed in R6).

__global__ __launch_bounds__(256) void k_agg_g5(const __half* __restrict__ g,
                                                const int* __restrict__ row_start,
                                                const int* __restrict__ row_end,
                                                const int* __restrict__ csr,
                                                const float* __restrict__ dinv,
                                                const float* __restrict__ b4,
                                                const float* __restrict__ W5,
                                                __half* __restrict__ out) {
  constexpr int LG = 8, NPB = 32, SPB = SLICE / NPB, RP = 36;
  __shared__ float sW[32 * 16];
  __shared__ float rows[NPB * RP];
  __shared__ float sdi[NPB];
  int t = threadIdx.x;
  for (int k = t; k < 512; k += 256) sW[k] = W5[k];
  int bi = blockIdx.x;
  int vb = (bi & 7) * SPB + (bi >> 3);
  int nbase = vb * NPB;
  int q = t & (LG - 1), nl = t / LG;
  int i = nbase + nl;
  int gl = (t & 63) & ~(LG - 1);
  float4 acc = agg_core_h<32, 16>(g, csr, row_start[i], row_end[i], q, gl);
  float di = dinv[i];
  float4 bb = *(const float4*)(b4 + q * 4);
  acc.x = fmaxf(fmaf(di, acc.x, bb.x), 0.f);
  acc.y = fmaxf(fmaf(di, acc.y, bb.y), 0.f);
  acc.z = fmaxf(fmaf(di, acc.z, bb.z), 0.f);
  acc.w = fmaxf(fmaf(di, acc.w, bb.w), 0.f);
  *(float4*)&rows[nl * RP + q * 4] = acc;
  if (q == 0) sdi[nl] = di;
  __syncthreads();
  int n2 = t >> 3, c = t & 7;                  // 8 threads/node, 2 outs each
  float o0 = 0.f, o1 = 0.f;
  const float* row = &rows[n2 * RP];
#pragma unroll
  for (int k = 0; k < 32; ++k) {
    float rv = row[k];
    o0 = fmaf(rv, sW[k * 16 + c * 2],     o0);
    o1 = fmaf(rv, sW[k * 16 + c * 2 + 1], o1);
  }
  float d2 = sdi[n2];
  *(__half2*)(out + (size_t)(nbase + n2) * 16 + c * 2)
      = __floats2half2_rn(o0 * d2, o1 * d2);
}

// ---- K6: h5 = relu(dinv·Σg5 + b5); out = relu(h5@fW1+fb1)@fW2+fb2 --------
// Gather reads fp16 g5; final output stays fp32. EPI=16.

__global__ __launch_bounds__(256) void k_agg_mlp(const __half* __restrict__ g,
                                                 const int* __restrict__ row_start,
                                                 const int* __restrict__ row_end,
                                                 const int* __restrict__ csr,
                                                 const float* __restrict__ dinv,
                                                 const float* __restrict__ b5,
                                                 const float* __restrict__ fW1,
                                                 const float* __restrict__ fb1,
                                                 const float* __restrict__ fW2,
                                                 const float* __restrict__ fb2,
                                                 float* __restrict__ out) {
  constexpr int LG = 4, NPB = 64, SPB = SLICE / NPB, RP = 20;
  __shared__ float sW1[256], sW2[144], sB1[16], sB2[9];
  __shared__ float rows[NPB * RP];
  __shared__ float zrows[NPB * RP];
  __shared__ float ost[NPB * 9];
  int t = threadIdx.x;
  sW1[t] = fW1[t];
  if (t < 144) sW2[t] = fW2[t];
  if (t < 16)  sB1[t] = fb1[t];
  if (t < 9)   sB2[t] = fb2[t];
  int bi = blockIdx.x;
  int vb = (bi & 7) * SPB + (bi >> 3);
  int nbase = vb * NPB;
  int q = t & (LG - 1), nl = t / LG;
  int i = nbase + nl;
  int gl = (t & 63) & ~(LG - 1);
  float4 acc = agg_core_h<16, 16>(g, csr, row_start[i], row_end[i], q, gl);
  float di = dinv[i];
  float4 bb = *(const float4*)(b5 + q * 4);
  acc.x = fmaxf(fmaf(di, acc.x, bb.x), 0.f);
  acc.y = fmaxf(fmaf(di, acc.y, bb.y), 0.f);
  acc.z = fmaxf(fmaf(di, acc.z, bb.z), 0.f);
  acc.w = fmaxf(fmaf(di, acc.w, bb.w), 0.f);
  *(float4*)&rows[nl * RP + q * 4] = acc;
  __syncthreads();
  int n2 = t >> 2, c = t & 3;                  // 4 threads/node
  {                                            // z = relu(h5@fW1+fb1), 4 each
    float o[4];
#pragma unroll
    for (int j = 0; j < 4; ++j) o[j] = sB1[c * 4 + j];
    const float* row = &rows[n2 * RP];
#pragma unroll
    for (int k = 0; k < 16; ++k) {
      float rv = row[k];
#pragma unroll
      for (int j = 0; j < 4; ++j) o[j] = fmaf(rv, sW1[k * 16 + c * 4 + j], o[j]);
    }
    float* zp = &zrows[n2 * RP + c * 4];
#pragma unroll
    for (int j = 0; j < 4; ++j) zp[j] = fmaxf(o[j], 0.f);
  }
  __syncthreads();
  if (c < 3) {                                 // 3 outs each (3x3 = 9)
    float o[3];
#pragma unroll
    for (int j = 0; j < 3; ++j) o[j] = sB2[c * 3 + j];
    const float* zp = &zrows[n2 * RP];
#pragma unroll
    for (int k = 0; k < 16; ++k) {
      float zv = zp[k];
#pragma unroll
      for (int j = 0; j < 3; ++j) o[j] = fmaf(zv, sW2[k * 9 + c * 3 + j], o[j]);
    }
#pragma unroll
    for (int j = 0; j < 3; ++j) ost[n2 * 9 + c * 3 + j] = o[j];
  }
  __syncthreads();
  float* ob = out + (size_t)nbase * 9;
  for (int k = t; k < NPB * 9; k += 256) ob[k] = ost[k];
}

// ---------------- launch ----------------

extern "C" void kernel_launch(void* const* d_in, const int* in_sizes, int n_in,
                              void* d_out, int out_size, void* d_ws, size_t ws_size,
                              hipStream_t stream) {
  const float* x   = (const float*)d_in[0];
  const int*   ei  = (const int*)d_in[1];
  const float* W1  = (const float*)d_in[2];
  const float* b1  = (const float*)d_in[3];
  const float* W2  = (const float*)d_in[4];
  const float* b2  = (const float*)d_in[5];
  const float* W3  = (const float*)d_in[6];
  const float* b3  = (const float*)d_in[7];
  const float* W4  = (const float*)d_in[8];
  const float* b4  = (const float*)d_in[9];
  const float* W5  = (const float*)d_in[10];
  const float* b5  = (const float*)d_in[11];
  const float* fW1 = (const float*)d_in[12];
  const float* fb1 = (const float*)d_in[13];
  const float* fW2 = (const float*)d_in[14];
  const float* fb2 = (const float*)d_in[15];
  float* out = (float*)d_out;

  char* ws = (char*)d_ws;
  size_t off = 0;
  auto alloc = [&](size_t bytes) -> char* {
    char* p = ws + off;
    off += (bytes + 255) & ~(size_t)255;
    return p;
  };
  int*   counts  = (int*)  alloc((size_t)NBLK * NBKT * 4);
  int*   basesT  = (int*)  alloc((size_t)NBKT * NBLK * 4);
  int*   btot    = (int*)  alloc((size_t)NBKT * 4);
  unsigned int* pairs = (unsigned int*)alloc((size_t)NEDGE * 4);
  int*   rs_     = (int*)  alloc((size_t)NN * 4);
  int*   re_     = (int*)  alloc((size_t)NN * 4);
  float* dinv    = (float*)alloc((size_t)NN * 4);
  int*   csr     = (int*)  alloc((size_t)ETOT * 4);
  __half* H16a   = (__half*)alloc((size_t)NN * 16 * 2);   // g0, then g5
  __half* H16b   = (__half*)alloc((size_t)NN * 16 * 2);   // g1
  __half* H32a   = (__half*)alloc((size_t)NN * 32 * 2);   // g2
  __half* H32b   = (__half*)alloc((size_t)NN * 32 * 2);   // g4

  k_count<<<NBLK, 256, 0, stream>>>(ei, counts);
  k_scan <<<NBKT, 256, 0, stream>>>(counts, basesT, btot);
  k_scat <<<NBLK, 256, 0, stream>>>(ei, basesT, btot, pairs);
  // k_build + fused K1: csr/dinv/bounds + g0 = dinv⊙(x@W1) -> fp16
  k_build<<<NBKT, 256, 0, stream>>>(pairs, btot, x, W1, rs_, re_, dinv, csr, H16a);

  // K2: g1 = dinv⊙relu(dinv·Σg0 + b1) -> fp16
  k_agg_ep16<<<NN / 64, 256, 0, stream>>>(H16a, rs_, re_, csr, dinv, b1, H16b);
  // K3: g2 = dinv⊙relu((dinv·Σg1)@W2 + b2) -> fp16
  k_agg_g2<<<NN / 64, 256, 0, stream>>>(H16b, rs_, re_, csr, dinv, W2, b2, H32a);
  // K4: g4 = dinv⊙(relu((dinv·Σg2)@W3+b3)@W4) -> fp16
  k_agg_g34<<<NN / 32, 256, 0, stream>>>(H32a, rs_, re_, csr, dinv, W3, b3, W4, H32b);
  // K5: g5 = dinv⊙(relu(dinv·Σg4 + b4)@W5) -> fp16 (reuses H16a, g0 dead)
  k_agg_g5<<<NN / 32, 256, 0, stream>>>(H32b, rs_, re_, csr, dinv, b4, W5, H16a);
  // K6: head MLP on h5 = relu(dinv·Σg5 + b5), fp32 out
  k_agg_mlp<<<NN / 64, 256, 0, stream>>>(H16a, rs_, re_, csr, dinv, b5,
                                         fW1, fb1, fW2, fb2, out);
}